// Round 8
// baseline (178.983 us; speedup 1.0000x reference)
//
#include <hip/hip_runtime.h>
#include <math.h>

#define N 8192
#define FIN 129
#define D 64
#define TEMP 10.0f
#define LOG2E 1.4426950408889634f
#define SPLIT 64              // j-slices for all N^2 passes (occupancy lever)
#define RG 4                  // row-groups per wave -> 64 rows/wave
#define BROWS 256             // 4 waves * 64 rows

typedef _Float16 f16x8 __attribute__((ext_vector_type(8)));
typedef float    f32x4 __attribute__((ext_vector_type(4)));

#define MFMA16(A, B, C) __builtin_amdgcn_mfma_f32_16x16x32_f16((A), (B), (C), 0, 0, 0)

// Validated geometry (swapped operands, A=k-rows, B=q-rows):
//   B-frag: q row i = i0 + rg*16 + lr   (lr = lane&15)  -> lane's output ROW
//   A-frag: k row j = j0 + rf*16 + lr
//   C elem e: col j = j0 + rf*16 + lg*4 + e  (lg = lane>>4)
// Per lane: 4 consecutive output cols of ONE row -> float4 stores, per-element rinv.

// ---------------- Kernel 1: q = mlp_q(x), k = mlp_k(x) -> f16 ----------------
__global__ __launch_bounds__(256) void k_mlp(
    const float* __restrict__ x,
    const float* __restrict__ Wq1, const float* __restrict__ bq1,
    const float* __restrict__ Wq2, const float* __restrict__ bq2,
    const float* __restrict__ Wk1, const float* __restrict__ bk1,
    const float* __restrict__ Wk2, const float* __restrict__ bk2,
    _Float16* __restrict__ qo, _Float16* __restrict__ ko)
{
    __shared__ float xs[4][FIN];
    __shared__ float hqs[4][D];
    __shared__ float hks[4][D];
    const int wave = threadIdx.x >> 6;
    const int lane = threadIdx.x & 63;
    const int row  = (blockIdx.x << 2) + wave;

    const float* xr = x + row * FIN;
    xs[wave][lane]      = xr[lane];
    xs[wave][64 + lane] = xr[64 + lane];
    if (lane == 0) xs[wave][128] = xr[128];
    __syncthreads();

    float aq = bq1[lane], ak = bk1[lane];
    for (int f = 0; f < FIN; ++f) {
        const float xv = xs[wave][f];
        aq = fmaf(xv, Wq1[f * D + lane], aq);
        ak = fmaf(xv, Wk1[f * D + lane], ak);
    }
    hqs[wave][lane] = fmaxf(aq, 0.f);
    hks[wave][lane] = fmaxf(ak, 0.f);
    __syncthreads();

    float oq = bq2[lane], ok = bk2[lane];
    for (int t = 0; t < D; ++t) {
        oq = fmaf(hqs[wave][t], Wq2[t * D + lane], oq);
        ok = fmaf(hks[wave][t], Wk2[t * D + lane], ok);
    }
    qo[row * D + lane] = (_Float16)oq;
    ko[row * D + lane] = (_Float16)ok;
}

// ---------------- Pass 1: raw row max -> mpart[SPLIT][N] ----------------
// Wave owns 64 rows (RG=4 row-groups) x 128 cols; 16 MFMA per 4 k-loads.
__global__ __launch_bounds__(256) void k_max(
    const _Float16* __restrict__ q16, const _Float16* __restrict__ k16,
    float* __restrict__ mpart)
{
    const int tid  = threadIdx.x;
    const int wave = tid >> 6;
    const int lane = tid & 63;
    const int lr   = lane & 15;
    const int lg   = lane >> 4;
    const int i0   = blockIdx.x * BROWS + wave * 64;
    const int jbase = blockIdx.y * (N / SPLIT);

    f16x8 b[RG][2];
    #pragma unroll
    for (int rg = 0; rg < RG; ++rg) {
        b[rg][0] = *reinterpret_cast<const f16x8*>(&q16[(i0 + rg * 16 + lr) * D + 8 * lg]);
        b[rg][1] = *reinterpret_cast<const f16x8*>(&q16[(i0 + rg * 16 + lr) * D + 32 + 8 * lg]);
    }

    float mx[RG];
    #pragma unroll
    for (int rg = 0; rg < RG; ++rg) mx[rg] = -INFINITY;

    #pragma unroll 2
    for (int cf = 0; cf < (N / SPLIT) / 32; ++cf) {
        const int j0 = jbase + cf * 32;
        #pragma unroll
        for (int rf = 0; rf < 2; ++rf) {
            const f16x8 a0 = *reinterpret_cast<const f16x8*>(&k16[(j0 + rf * 16 + lr) * D + 8 * lg]);
            const f16x8 a1 = *reinterpret_cast<const f16x8*>(&k16[(j0 + rf * 16 + lr) * D + 32 + 8 * lg]);
            #pragma unroll
            for (int rg = 0; rg < RG; ++rg) {
                f32x4 acc = {0.f, 0.f, 0.f, 0.f};
                acc = MFMA16(a0, b[rg][0], acc);
                acc = MFMA16(a1, b[rg][1], acc);
                mx[rg] = fmaxf(mx[rg], fmaxf(fmaxf(acc[0], acc[1]), fmaxf(acc[2], acc[3])));
            }
        }
    }

    #pragma unroll
    for (int rg = 0; rg < RG; ++rg) {
        mx[rg] = fmaxf(mx[rg], __shfl_xor(mx[rg], 16));
        mx[rg] = fmaxf(mx[rg], __shfl_xor(mx[rg], 32));
    }
    if (lane < 16) {
        #pragma unroll
        for (int rg = 0; rg < RG; ++rg)
            mpart[blockIdx.y * N + i0 + rg * 16 + lr] = mx[rg];
    }
}

// ---------------- rinv[j] = TEMP*log2e / m_j ----------------
__global__ __launch_bounds__(256) void k_fin1(const float* __restrict__ mp, float* __restrict__ rinv)
{
    const int j = blockIdx.x * 256 + threadIdx.x;
    float m = mp[j];
    #pragma unroll 8
    for (int s = 1; s < SPLIT; ++s) m = fmaxf(m, mp[s * N + j]);
    rinv[j] = TEMP * LOG2E / m;
}

// ---------------- Pass 2: scaled row max + sum -> M2part, Lpart ----------------
__global__ __launch_bounds__(256) void k_sumL(
    const _Float16* __restrict__ q16, const _Float16* __restrict__ k16,
    const float* __restrict__ rinv,
    float* __restrict__ M2part, float* __restrict__ Lpart)
{
    const int tid  = threadIdx.x;
    const int wave = tid >> 6;
    const int lane = tid & 63;
    const int lr   = lane & 15;
    const int lg   = lane >> 4;
    const int i0   = blockIdx.x * BROWS + wave * 64;
    const int jbase = blockIdx.y * (N / SPLIT);

    f16x8 b[RG][2];
    #pragma unroll
    for (int rg = 0; rg < RG; ++rg) {
        b[rg][0] = *reinterpret_cast<const f16x8*>(&q16[(i0 + rg * 16 + lr) * D + 8 * lg]);
        b[rg][1] = *reinterpret_cast<const f16x8*>(&q16[(i0 + rg * 16 + lr) * D + 32 + 8 * lg]);
    }

    float mx[RG], sm[RG];
    #pragma unroll
    for (int rg = 0; rg < RG; ++rg) { mx[rg] = -INFINITY; sm[rg] = 0.f; }

    #pragma unroll 2
    for (int cf = 0; cf < (N / SPLIT) / 32; ++cf) {
        const int j0 = jbase + cf * 32;
        f32x4 acc[RG][2];
        float4 r4[2];
        #pragma unroll
        for (int rf = 0; rf < 2; ++rf) {
            const f16x8 a0 = *reinterpret_cast<const f16x8*>(&k16[(j0 + rf * 16 + lr) * D + 8 * lg]);
            const f16x8 a1 = *reinterpret_cast<const f16x8*>(&k16[(j0 + rf * 16 + lr) * D + 32 + 8 * lg]);
            r4[rf] = *reinterpret_cast<const float4*>(&rinv[j0 + rf * 16 + lg * 4]);
            #pragma unroll
            for (int rg = 0; rg < RG; ++rg) {
                f32x4 t = {0.f, 0.f, 0.f, 0.f};
                t = MFMA16(a0, b[rg][0], t);
                t = MFMA16(a1, b[rg][1], t);
                acc[rg][rf] = t;
            }
        }
        #pragma unroll
        for (int rg = 0; rg < RG; ++rg) {
            float s[8];
            s[0] = acc[rg][0][0] * r4[0].x; s[1] = acc[rg][0][1] * r4[0].y;
            s[2] = acc[rg][0][2] * r4[0].z; s[3] = acc[rg][0][3] * r4[0].w;
            s[4] = acc[rg][1][0] * r4[1].x; s[5] = acc[rg][1][1] * r4[1].y;
            s[6] = acc[rg][1][2] * r4[1].z; s[7] = acc[rg][1][3] * r4[1].w;
            const float tm = fmaxf(fmaxf(fmaxf(s[0], s[1]), fmaxf(s[2], s[3])),
                                   fmaxf(fmaxf(s[4], s[5]), fmaxf(s[6], s[7])));
            const float nm = fmaxf(mx[rg], tm);
            float add = 0.f;
            #pragma unroll
            for (int t = 0; t < 8; ++t) add += exp2f(s[t] - nm);
            sm[rg] = fmaf(sm[rg], exp2f(mx[rg] - nm), add);
            mx[rg] = nm;
        }
    }

    #pragma unroll
    for (int rg = 0; rg < RG; ++rg) {
        #pragma unroll
        for (int off = 16; off <= 32; off <<= 1) {
            const float om = __shfl_xor(mx[rg], off);
            const float os = __shfl_xor(sm[rg], off);
            const float nm = fmaxf(mx[rg], om);
            sm[rg] = sm[rg] * exp2f(mx[rg] - nm) + os * exp2f(om - nm);
            mx[rg] = nm;
        }
    }
    if (lane < 16) {
        #pragma unroll
        for (int rg = 0; rg < RG; ++rg) {
            M2part[blockIdx.y * N + i0 + rg * 16 + lr] = mx[rg];
            Lpart [blockIdx.y * N + i0 + rg * 16 + lr] = sm[rg];
        }
    }
}

// ---------------- M2[i], Linv[i] from split partials ----------------
__global__ __launch_bounds__(256) void k_finML(
    const float* __restrict__ M2p, const float* __restrict__ Lp,
    float* __restrict__ M2, float* __restrict__ Linv)
{
    const int i = blockIdx.x * 256 + threadIdx.x;
    float M = M2p[i];
    #pragma unroll 8
    for (int s = 1; s < SPLIT; ++s) M = fmaxf(M, M2p[s * N + i]);
    float L = 0.f;
    #pragma unroll 8
    for (int s = 0; s < SPLIT; ++s) L += Lp[s * N + i] * exp2f(M2p[s * N + i] - M);
    M2[i] = M;
    Linv[i] = 1.f / L;
}

// ---------------- Pass 3: out = exp2(s2 - M2_i) * Linv_i ----------------
// grid (N/256, SPLIT); wave computes 64 rows x 128 cols; float4 stores.
__global__ __launch_bounds__(256) void k_write(
    const _Float16* __restrict__ q16, const _Float16* __restrict__ k16,
    const float* __restrict__ rinv, const float* __restrict__ M2,
    const float* __restrict__ Linv, float* __restrict__ out)
{
    const int tid  = threadIdx.x;
    const int wave = tid >> 6;
    const int lane = tid & 63;
    const int lr   = lane & 15;
    const int lg   = lane >> 4;
    const int i0   = blockIdx.x * BROWS + wave * 64;
    const int jbase = blockIdx.y * (N / SPLIT);

    f16x8 b[RG][2];
    float M2i[RG], Lvi[RG];
    #pragma unroll
    for (int rg = 0; rg < RG; ++rg) {
        b[rg][0] = *reinterpret_cast<const f16x8*>(&q16[(i0 + rg * 16 + lr) * D + 8 * lg]);
        b[rg][1] = *reinterpret_cast<const f16x8*>(&q16[(i0 + rg * 16 + lr) * D + 32 + 8 * lg]);
        M2i[rg] = M2[i0 + rg * 16 + lr];
        Lvi[rg] = Linv[i0 + rg * 16 + lr];
    }

    #pragma unroll 2
    for (int cf = 0; cf < (N / SPLIT) / 32; ++cf) {
        const int j0 = jbase + cf * 32;
        #pragma unroll
        for (int rf = 0; rf < 2; ++rf) {
            const f16x8 a0 = *reinterpret_cast<const f16x8*>(&k16[(j0 + rf * 16 + lr) * D + 8 * lg]);
            const f16x8 a1 = *reinterpret_cast<const f16x8*>(&k16[(j0 + rf * 16 + lr) * D + 32 + 8 * lg]);
            const float4 r4 = *reinterpret_cast<const float4*>(&rinv[j0 + rf * 16 + lg * 4]);
            #pragma unroll
            for (int rg = 0; rg < RG; ++rg) {
                f32x4 acc = {0.f, 0.f, 0.f, 0.f};
                acc = MFMA16(a0, b[rg][0], acc);
                acc = MFMA16(a1, b[rg][1], acc);
                float4 o;
                o.x = exp2f(fmaf(acc[0], r4.x, -M2i[rg])) * Lvi[rg];
                o.y = exp2f(fmaf(acc[1], r4.y, -M2i[rg])) * Lvi[rg];
                o.z = exp2f(fmaf(acc[2], r4.z, -M2i[rg])) * Lvi[rg];
                o.w = exp2f(fmaf(acc[3], r4.w, -M2i[rg])) * Lvi[rg];
                *reinterpret_cast<float4*>(
                    &out[(size_t)(i0 + rg * 16 + lr) * N + j0 + rf * 16 + lg * 4]) = o;
            }
        }
    }
}

extern "C" void kernel_launch(void* const* d_in, const int* in_sizes, int n_in,
                              void* d_out, int out_size, void* d_ws, size_t ws_size,
                              hipStream_t stream)
{
    const float* x   = (const float*)d_in[0];
    const float* Wq1 = (const float*)d_in[1];
    const float* bq1 = (const float*)d_in[2];
    const float* Wq2 = (const float*)d_in[3];
    const float* bq2 = (const float*)d_in[4];
    const float* Wk1 = (const float*)d_in[5];
    const float* bk1 = (const float*)d_in[6];
    const float* Wk2 = (const float*)d_in[7];
    const float* bk2 = (const float*)d_in[8];

    float* out = (float*)d_out;

    _Float16* q16 = (_Float16*)d_ws;                       // 1 MB
    _Float16* k16 = q16 + (size_t)N * D;                   // 1 MB
    float* mpart  = (float*)(k16 + (size_t)N * D);         // SPLIT*N = 2 MB
    float* M2part = mpart + (size_t)SPLIT * N;             // 2 MB
    float* Lpart  = M2part + (size_t)SPLIT * N;            // 2 MB
    float* rinv   = Lpart + (size_t)SPLIT * N;             // N
    float* M2     = rinv + N;                              // N
    float* Linv   = M2 + N;                                // N

    k_mlp  <<<N / 4, 256, 0, stream>>>(x, Wq1, bq1, Wq2, bq2, Wk1, bk1, Wk2, bk2, q16, k16);
    k_max  <<<dim3(N / BROWS, SPLIT), 256, 0, stream>>>(q16, k16, mpart);
    k_fin1 <<<N / 256, 256, 0, stream>>>(mpart, rinv);
    k_sumL <<<dim3(N / BROWS, SPLIT), 256, 0, stream>>>(q16, k16, rinv, M2part, Lpart);
    k_finML<<<N / 256, 256, 0, stream>>>(M2part, Lpart, M2, Linv);
    k_write<<<dim3(N / BROWS, SPLIT), 256, 0, stream>>>(q16, k16, rinv, M2, Linv, out);
}

// Round 10
// 172.415 us; speedup vs baseline: 1.0381x; 1.0381x over previous
//
#include <hip/hip_runtime.h>
#include <math.h>

#define N 8192
#define FIN 129
#define D 64
#define TEMP 10.0f
#define LOG2E 1.4426950408889634f
#define SPLIT 16              // j-slices for all N^2 passes (R7-validated sweet spot)
#define RG 4                  // row-groups per wave -> 64 rows/wave
#define BROWS 256             // 4 waves * 64 rows

typedef _Float16 f16x8 __attribute__((ext_vector_type(8)));
typedef float    f32x4 __attribute__((ext_vector_type(4)));

#define MFMA16(A, B, C) __builtin_amdgcn_mfma_f32_16x16x32_f16((A), (B), (C), 0, 0, 0)

// Validated geometry (swapped operands, A=k-rows, B=q-rows):
//   B-frag: q row i = i0 + rg*16 + lr   (lr = lane&15)  -> lane's output ROW
//   A-frag: k row j = j0 + rf*16 + lr
//   C elem e: col j = j0 + rf*16 + lg*4 + e  (lg = lane>>4)
// Per lane: 4 consecutive output cols of ONE row -> float4 stores, per-element rinv.
//
// No-shift softmax: s2 = TEMP*log2e * acc/m_j is intrinsically bounded (|s2|<~30
// since m_j = max of 8192 ~Gaussian scores >= ~3.5 sigma), so exp2(s2) never
// overflows f32 and no row-max shift is needed. Identical MFMA+scale arithmetic
// in pass 2 and pass 3 => consistent numerator/denominator.

// ---------------- Kernel 1: q = mlp_q(x), k = mlp_k(x) -> f16 ----------------
__global__ __launch_bounds__(256) void k_mlp(
    const float* __restrict__ x,
    const float* __restrict__ Wq1, const float* __restrict__ bq1,
    const float* __restrict__ Wq2, const float* __restrict__ bq2,
    const float* __restrict__ Wk1, const float* __restrict__ bk1,
    const float* __restrict__ Wk2, const float* __restrict__ bk2,
    _Float16* __restrict__ qo, _Float16* __restrict__ ko)
{
    __shared__ float xs[4][FIN];
    __shared__ float hqs[4][D];
    __shared__ float hks[4][D];
    const int wave = threadIdx.x >> 6;
    const int lane = threadIdx.x & 63;
    const int row  = (blockIdx.x << 2) + wave;

    const float* xr = x + row * FIN;
    xs[wave][lane]      = xr[lane];
    xs[wave][64 + lane] = xr[64 + lane];
    if (lane == 0) xs[wave][128] = xr[128];
    __syncthreads();

    float aq = bq1[lane], ak = bk1[lane];
    for (int f = 0; f < FIN; ++f) {
        const float xv = xs[wave][f];
        aq = fmaf(xv, Wq1[f * D + lane], aq);
        ak = fmaf(xv, Wk1[f * D + lane], ak);
    }
    hqs[wave][lane] = fmaxf(aq, 0.f);
    hks[wave][lane] = fmaxf(ak, 0.f);
    __syncthreads();

    float oq = bq2[lane], ok = bk2[lane];
    for (int t = 0; t < D; ++t) {
        oq = fmaf(hqs[wave][t], Wq2[t * D + lane], oq);
        ok = fmaf(hks[wave][t], Wk2[t * D + lane], ok);
    }
    qo[row * D + lane] = (_Float16)oq;
    ko[row * D + lane] = (_Float16)ok;
}

// ---------------- Pass 1: raw row max -> mpart[SPLIT][N] (R7-exact) ----------------
__global__ __launch_bounds__(256) void k_max(
    const _Float16* __restrict__ q16, const _Float16* __restrict__ k16,
    float* __restrict__ mpart)
{
    const int tid  = threadIdx.x;
    const int wave = tid >> 6;
    const int lane = tid & 63;
    const int lr   = lane & 15;
    const int lg   = lane >> 4;
    const int i0   = blockIdx.x * BROWS + wave * 64;
    const int jbase = blockIdx.y * (N / SPLIT);

    f16x8 b[RG][2];
    #pragma unroll
    for (int rg = 0; rg < RG; ++rg) {
        b[rg][0] = *reinterpret_cast<const f16x8*>(&q16[(i0 + rg * 16 + lr) * D + 8 * lg]);
        b[rg][1] = *reinterpret_cast<const f16x8*>(&q16[(i0 + rg * 16 + lr) * D + 32 + 8 * lg]);
    }

    float mx[RG];
    #pragma unroll
    for (int rg = 0; rg < RG; ++rg) mx[rg] = -INFINITY;

    for (int cf = 0; cf < (N / SPLIT) / 32; ++cf) {
        const int j0 = jbase + cf * 32;
        #pragma unroll
        for (int rf = 0; rf < 2; ++rf) {
            const f16x8 a0 = *reinterpret_cast<const f16x8*>(&k16[(j0 + rf * 16 + lr) * D + 8 * lg]);
            const f16x8 a1 = *reinterpret_cast<const f16x8*>(&k16[(j0 + rf * 16 + lr) * D + 32 + 8 * lg]);
            #pragma unroll
            for (int rg = 0; rg < RG; ++rg) {
                f32x4 acc = {0.f, 0.f, 0.f, 0.f};
                acc = MFMA16(a0, b[rg][0], acc);
                acc = MFMA16(a1, b[rg][1], acc);
                mx[rg] = fmaxf(mx[rg], fmaxf(fmaxf(acc[0], acc[1]), fmaxf(acc[2], acc[3])));
            }
        }
    }

    #pragma unroll
    for (int rg = 0; rg < RG; ++rg) {
        mx[rg] = fmaxf(mx[rg], __shfl_xor(mx[rg], 16));
        mx[rg] = fmaxf(mx[rg], __shfl_xor(mx[rg], 32));
    }
    if (lane < 16) {
        #pragma unroll
        for (int rg = 0; rg < RG; ++rg)
            mpart[blockIdx.y * N + i0 + rg * 16 + lr] = mx[rg];
    }
}

// ---------------- rinv[j] = TEMP*log2e / m_j ----------------
__global__ __launch_bounds__(256) void k_fin1(const float* __restrict__ mp, float* __restrict__ rinv)
{
    const int j = blockIdx.x * 256 + threadIdx.x;
    float m = mp[j];
    #pragma unroll
    for (int s = 1; s < SPLIT; ++s) m = fmaxf(m, mp[s * N + j]);
    rinv[j] = TEMP * LOG2E / m;
}

// ---------------- Pass 2: Lpart[s][i] = sum_j exp2(s2_ij)  (no shift) ----------------
__global__ __launch_bounds__(256) void k_sumL(
    const _Float16* __restrict__ q16, const _Float16* __restrict__ k16,
    const float* __restrict__ rinv, float* __restrict__ Lpart)
{
    const int tid  = threadIdx.x;
    const int wave = tid >> 6;
    const int lane = tid & 63;
    const int lr   = lane & 15;
    const int lg   = lane >> 4;
    const int i0   = blockIdx.x * BROWS + wave * 64;
    const int jbase = blockIdx.y * (N / SPLIT);

    f16x8 b[RG][2];
    #pragma unroll
    for (int rg = 0; rg < RG; ++rg) {
        b[rg][0] = *reinterpret_cast<const f16x8*>(&q16[(i0 + rg * 16 + lr) * D + 8 * lg]);
        b[rg][1] = *reinterpret_cast<const f16x8*>(&q16[(i0 + rg * 16 + lr) * D + 32 + 8 * lg]);
    }

    float sm[RG];
    #pragma unroll
    for (int rg = 0; rg < RG; ++rg) sm[rg] = 0.f;

    for (int cf = 0; cf < (N / SPLIT) / 32; ++cf) {
        const int j0 = jbase + cf * 32;
        #pragma unroll
        for (int rf = 0; rf < 2; ++rf) {
            const f16x8 a0 = *reinterpret_cast<const f16x8*>(&k16[(j0 + rf * 16 + lr) * D + 8 * lg]);
            const f16x8 a1 = *reinterpret_cast<const f16x8*>(&k16[(j0 + rf * 16 + lr) * D + 32 + 8 * lg]);
            const float4 r4 = *reinterpret_cast<const float4*>(&rinv[j0 + rf * 16 + lg * 4]);
            #pragma unroll
            for (int rg = 0; rg < RG; ++rg) {
                f32x4 acc = {0.f, 0.f, 0.f, 0.f};
                acc = MFMA16(a0, b[rg][0], acc);
                acc = MFMA16(a1, b[rg][1], acc);
                sm[rg] += exp2f(acc[0] * r4.x) + exp2f(acc[1] * r4.y)
                        + exp2f(acc[2] * r4.z) + exp2f(acc[3] * r4.w);
            }
        }
    }

    #pragma unroll
    for (int rg = 0; rg < RG; ++rg) {
        sm[rg] += __shfl_xor(sm[rg], 16);
        sm[rg] += __shfl_xor(sm[rg], 32);
    }
    if (lane < 16) {
        #pragma unroll
        for (int rg = 0; rg < RG; ++rg)
            Lpart[blockIdx.y * N + i0 + rg * 16 + lr] = sm[rg];
    }
}

// ---------------- Linv[i] = 1 / sum_s Lpart[s][i] ----------------
__global__ __launch_bounds__(256) void k_finL(const float* __restrict__ Lp, float* __restrict__ Linv)
{
    const int i = blockIdx.x * 256 + threadIdx.x;
    float L = 0.f;
    #pragma unroll
    for (int s = 0; s < SPLIT; ++s) L += Lp[s * N + i];
    Linv[i] = 1.f / L;
}

// ---------------- Pass 3: out = exp2(s2) * Linv_i (no shift, NT stores) ----------------
__global__ __launch_bounds__(256) void k_write(
    const _Float16* __restrict__ q16, const _Float16* __restrict__ k16,
    const float* __restrict__ rinv, const float* __restrict__ Linv,
    float* __restrict__ out)
{
    const int tid  = threadIdx.x;
    const int wave = tid >> 6;
    const int lane = tid & 63;
    const int lr   = lane & 15;
    const int lg   = lane >> 4;
    const int i0   = blockIdx.x * BROWS + wave * 64;
    const int jbase = blockIdx.y * (N / SPLIT);

    f16x8 b[RG][2];
    float Lvi[RG];
    #pragma unroll
    for (int rg = 0; rg < RG; ++rg) {
        b[rg][0] = *reinterpret_cast<const f16x8*>(&q16[(i0 + rg * 16 + lr) * D + 8 * lg]);
        b[rg][1] = *reinterpret_cast<const f16x8*>(&q16[(i0 + rg * 16 + lr) * D + 32 + 8 * lg]);
        Lvi[rg] = Linv[i0 + rg * 16 + lr];
    }

    for (int cf = 0; cf < (N / SPLIT) / 32; ++cf) {
        const int j0 = jbase + cf * 32;
        #pragma unroll
        for (int rf = 0; rf < 2; ++rf) {
            const f16x8 a0 = *reinterpret_cast<const f16x8*>(&k16[(j0 + rf * 16 + lr) * D + 8 * lg]);
            const f16x8 a1 = *reinterpret_cast<const f16x8*>(&k16[(j0 + rf * 16 + lr) * D + 32 + 8 * lg]);
            const float4 r4 = *reinterpret_cast<const float4*>(&rinv[j0 + rf * 16 + lg * 4]);
            #pragma unroll
            for (int rg = 0; rg < RG; ++rg) {
                f32x4 acc = {0.f, 0.f, 0.f, 0.f};
                acc = MFMA16(a0, b[rg][0], acc);
                acc = MFMA16(a1, b[rg][1], acc);
                f32x4 o;
                o[0] = exp2f(acc[0] * r4.x) * Lvi[rg];
                o[1] = exp2f(acc[1] * r4.y) * Lvi[rg];
                o[2] = exp2f(acc[2] * r4.z) * Lvi[rg];
                o[3] = exp2f(acc[3] * r4.w) * Lvi[rg];
                __builtin_nontemporal_store(o,
                    reinterpret_cast<f32x4*>(
                        &out[(size_t)(i0 + rg * 16 + lr) * N + j0 + rf * 16 + lg * 4]));
            }
        }
    }
}

extern "C" void kernel_launch(void* const* d_in, const int* in_sizes, int n_in,
                              void* d_out, int out_size, void* d_ws, size_t ws_size,
                              hipStream_t stream)
{
    const float* x   = (const float*)d_in[0];
    const float* Wq1 = (const float*)d_in[1];
    const float* bq1 = (const float*)d_in[2];
    const float* Wq2 = (const float*)d_in[3];
    const float* bq2 = (const float*)d_in[4];
    const float* Wk1 = (const float*)d_in[5];
    const float* bk1 = (const float*)d_in[6];
    const float* Wk2 = (const float*)d_in[7];
    const float* bk2 = (const float*)d_in[8];

    float* out = (float*)d_out;

    _Float16* q16 = (_Float16*)d_ws;                       // 1 MB
    _Float16* k16 = q16 + (size_t)N * D;                   // 1 MB
    float* mpart  = (float*)(k16 + (size_t)N * D);         // SPLIT*N
    float* Lpart  = mpart + (size_t)SPLIT * N;             // SPLIT*N
    float* rinv   = Lpart + (size_t)SPLIT * N;             // N
    float* Linv   = rinv + N;                              // N

    k_mlp  <<<N / 4, 256, 0, stream>>>(x, Wq1, bq1, Wq2, bq2, Wk1, bk1, Wk2, bk2, q16, k16);
    k_max  <<<dim3(N / BROWS, SPLIT), 256, 0, stream>>>(q16, k16, mpart);
    k_fin1 <<<N / 256, 256, 0, stream>>>(mpart, rinv);
    k_sumL <<<dim3(N / BROWS, SPLIT), 256, 0, stream>>>(q16, k16, rinv, Lpart);
    k_finL <<<N / 256, 256, 0, stream>>>(Lpart, Linv);
    k_write<<<dim3(N / BROWS, SPLIT), 256, 0, stream>>>(q16, k16, rinv, Linv, out);
}

// Round 11
// 147.870 us; speedup vs baseline: 1.2104x; 1.1660x over previous
//
#include <hip/hip_runtime.h>
#include <math.h>

#define N 8192
#define FIN 129
#define D 64
#define TEMP 10.0f
#define LOG2E 1.4426950408889634f
#define SPLIT_S 32            // j-slices for stats passes (occupancy: 4 blk/CU)
#define SPLIT_W 16            // j-slices for write pass (R7-validated)
#define RG 4                  // row-groups per wave -> 64 rows/wave
#define BROWS 256             // 4 waves * 64 rows

typedef _Float16 f16x8 __attribute__((ext_vector_type(8)));
typedef float    f32x4 __attribute__((ext_vector_type(4)));

#define MFMA16(A, B, C) __builtin_amdgcn_mfma_f32_16x16x32_f16((A), (B), (C), 0, 0, 0)

// Validated geometry (swapped operands, A=k-rows, B=q-rows):
//   B-frag: q row i = i0 + rg*16 + lr   (lr = lane&15)  -> lane's output ROW
//   A-frag: k row j = j0 + rf*16 + lr
//   C elem e: col j = j0 + rf*16 + lg*4 + e  (lg = lane>>4)
// No-shift softmax: |s2| = |TEMP*log2e*acc/m_j| <~ 30 (m_j = max of 8192
// ~Gaussian scores), exp2 never overflows f32; identical score arithmetic in
// pass 2/3 keeps numerator/denominator consistent.

// ---------------- Kernel 1: q = mlp_q(x), k = mlp_k(x) -> f16 ----------------
__global__ __launch_bounds__(256) void k_mlp(
    const float* __restrict__ x,
    const float* __restrict__ Wq1, const float* __restrict__ bq1,
    const float* __restrict__ Wq2, const float* __restrict__ bq2,
    const float* __restrict__ Wk1, const float* __restrict__ bk1,
    const float* __restrict__ Wk2, const float* __restrict__ bk2,
    _Float16* __restrict__ qo, _Float16* __restrict__ ko)
{
    __shared__ float xs[4][FIN];
    __shared__ float hqs[4][D];
    __shared__ float hks[4][D];
    const int wave = threadIdx.x >> 6;
    const int lane = threadIdx.x & 63;
    const int row  = (blockIdx.x << 2) + wave;

    const float* xr = x + row * FIN;
    xs[wave][lane]      = xr[lane];
    xs[wave][64 + lane] = xr[64 + lane];
    if (lane == 0) xs[wave][128] = xr[128];
    __syncthreads();

    float aq = bq1[lane], ak = bk1[lane];
    for (int f = 0; f < FIN; ++f) {
        const float xv = xs[wave][f];
        aq = fmaf(xv, Wq1[f * D + lane], aq);
        ak = fmaf(xv, Wk1[f * D + lane], ak);
    }
    hqs[wave][lane] = fmaxf(aq, 0.f);
    hks[wave][lane] = fmaxf(ak, 0.f);
    __syncthreads();

    float oq = bq2[lane], ok = bk2[lane];
    for (int t = 0; t < D; ++t) {
        oq = fmaf(hqs[wave][t], Wq2[t * D + lane], oq);
        ok = fmaf(hks[wave][t], Wk2[t * D + lane], ok);
    }
    qo[row * D + lane] = (_Float16)oq;
    ko[row * D + lane] = (_Float16)ok;
}

// ---------------- Pass 1: raw row max -> mpart[SPLIT_S][N] ----------------
__global__ __launch_bounds__(256) void k_max(
    const _Float16* __restrict__ q16, const _Float16* __restrict__ k16,
    float* __restrict__ mpart)
{
    const int tid  = threadIdx.x;
    const int wave = tid >> 6;
    const int lane = tid & 63;
    const int lr   = lane & 15;
    const int lg   = lane >> 4;
    const int i0   = blockIdx.x * BROWS + wave * 64;
    const int jbase = blockIdx.y * (N / SPLIT_S);

    f16x8 b[RG][2];
    #pragma unroll
    for (int rg = 0; rg < RG; ++rg) {
        b[rg][0] = *reinterpret_cast<const f16x8*>(&q16[(i0 + rg * 16 + lr) * D + 8 * lg]);
        b[rg][1] = *reinterpret_cast<const f16x8*>(&q16[(i0 + rg * 16 + lr) * D + 32 + 8 * lg]);
    }

    float mx[RG];
    #pragma unroll
    for (int rg = 0; rg < RG; ++rg) mx[rg] = -INFINITY;

    for (int cf = 0; cf < (N / SPLIT_S) / 32; ++cf) {
        const int j0 = jbase + cf * 32;
        #pragma unroll
        for (int rf = 0; rf < 2; ++rf) {
            const f16x8 a0 = *reinterpret_cast<const f16x8*>(&k16[(j0 + rf * 16 + lr) * D + 8 * lg]);
            const f16x8 a1 = *reinterpret_cast<const f16x8*>(&k16[(j0 + rf * 16 + lr) * D + 32 + 8 * lg]);
            #pragma unroll
            for (int rg = 0; rg < RG; ++rg) {
                f32x4 acc = {0.f, 0.f, 0.f, 0.f};
                acc = MFMA16(a0, b[rg][0], acc);
                acc = MFMA16(a1, b[rg][1], acc);
                mx[rg] = fmaxf(mx[rg], fmaxf(fmaxf(acc[0], acc[1]), fmaxf(acc[2], acc[3])));
            }
        }
    }

    #pragma unroll
    for (int rg = 0; rg < RG; ++rg) {
        mx[rg] = fmaxf(mx[rg], __shfl_xor(mx[rg], 16));
        mx[rg] = fmaxf(mx[rg], __shfl_xor(mx[rg], 32));
    }
    if (lane < 16) {
        #pragma unroll
        for (int rg = 0; rg < RG; ++rg)
            mpart[blockIdx.y * N + i0 + rg * 16 + lr] = mx[rg];
    }
}

// ---------------- rinv[j] = TEMP*log2e / m_j ----------------
__global__ __launch_bounds__(256) void k_fin1(const float* __restrict__ mp, float* __restrict__ rinv)
{
    const int j = blockIdx.x * 256 + threadIdx.x;
    float m = mp[j];
    #pragma unroll
    for (int s = 1; s < SPLIT_S; ++s) m = fmaxf(m, mp[s * N + j]);
    rinv[j] = TEMP * LOG2E / m;
}

// ---------------- Pass 2: Lpart[s][i] = sum_j exp2(s2_ij)  (no shift) ----------------
__global__ __launch_bounds__(256) void k_sumL(
    const _Float16* __restrict__ q16, const _Float16* __restrict__ k16,
    const float* __restrict__ rinv, float* __restrict__ Lpart)
{
    const int tid  = threadIdx.x;
    const int wave = tid >> 6;
    const int lane = tid & 63;
    const int lr   = lane & 15;
    const int lg   = lane >> 4;
    const int i0   = blockIdx.x * BROWS + wave * 64;
    const int jbase = blockIdx.y * (N / SPLIT_S);

    f16x8 b[RG][2];
    #pragma unroll
    for (int rg = 0; rg < RG; ++rg) {
        b[rg][0] = *reinterpret_cast<const f16x8*>(&q16[(i0 + rg * 16 + lr) * D + 8 * lg]);
        b[rg][1] = *reinterpret_cast<const f16x8*>(&q16[(i0 + rg * 16 + lr) * D + 32 + 8 * lg]);
    }

    float sm[RG];
    #pragma unroll
    for (int rg = 0; rg < RG; ++rg) sm[rg] = 0.f;

    for (int cf = 0; cf < (N / SPLIT_S) / 32; ++cf) {
        const int j0 = jbase + cf * 32;
        #pragma unroll
        for (int rf = 0; rf < 2; ++rf) {
            const f16x8 a0 = *reinterpret_cast<const f16x8*>(&k16[(j0 + rf * 16 + lr) * D + 8 * lg]);
            const f16x8 a1 = *reinterpret_cast<const f16x8*>(&k16[(j0 + rf * 16 + lr) * D + 32 + 8 * lg]);
            const float4 r4 = *reinterpret_cast<const float4*>(&rinv[j0 + rf * 16 + lg * 4]);
            #pragma unroll
            for (int rg = 0; rg < RG; ++rg) {
                f32x4 acc = {0.f, 0.f, 0.f, 0.f};
                acc = MFMA16(a0, b[rg][0], acc);
                acc = MFMA16(a1, b[rg][1], acc);
                sm[rg] += exp2f(acc[0] * r4.x) + exp2f(acc[1] * r4.y)
                        + exp2f(acc[2] * r4.z) + exp2f(acc[3] * r4.w);
            }
        }
    }

    #pragma unroll
    for (int rg = 0; rg < RG; ++rg) {
        sm[rg] += __shfl_xor(sm[rg], 16);
        sm[rg] += __shfl_xor(sm[rg], 32);
    }
    if (lane < 16) {
        #pragma unroll
        for (int rg = 0; rg < RG; ++rg)
            Lpart[blockIdx.y * N + i0 + rg * 16 + lr] = sm[rg];
    }
}

// ---------------- Linv[i] = 1 / sum_s Lpart[s][i] ----------------
__global__ __launch_bounds__(256) void k_finL(const float* __restrict__ Lp, float* __restrict__ Linv)
{
    const int i = blockIdx.x * 256 + threadIdx.x;
    float L = 0.f;
    #pragma unroll
    for (int s = 0; s < SPLIT_S; ++s) L += Lp[s * N + i];
    Linv[i] = 1.f / L;
}

// ---------------- Pass 3: out = exp2(s2) * Linv_i (plain float4 stores) ----------------
__global__ __launch_bounds__(256) void k_write(
    const _Float16* __restrict__ q16, const _Float16* __restrict__ k16,
    const float* __restrict__ rinv, const float* __restrict__ Linv,
    float* __restrict__ out)
{
    const int tid  = threadIdx.x;
    const int wave = tid >> 6;
    const int lane = tid & 63;
    const int lr   = lane & 15;
    const int lg   = lane >> 4;
    const int i0   = blockIdx.x * BROWS + wave * 64;
    const int jbase = blockIdx.y * (N / SPLIT_W);

    f16x8 b[RG][2];
    float Lvi[RG];
    #pragma unroll
    for (int rg = 0; rg < RG; ++rg) {
        b[rg][0] = *reinterpret_cast<const f16x8*>(&q16[(i0 + rg * 16 + lr) * D + 8 * lg]);
        b[rg][1] = *reinterpret_cast<const f16x8*>(&q16[(i0 + rg * 16 + lr) * D + 32 + 8 * lg]);
        Lvi[rg] = Linv[i0 + rg * 16 + lr];
    }

    for (int cf = 0; cf < (N / SPLIT_W) / 32; ++cf) {
        const int j0 = jbase + cf * 32;
        #pragma unroll
        for (int rf = 0; rf < 2; ++rf) {
            const f16x8 a0 = *reinterpret_cast<const f16x8*>(&k16[(j0 + rf * 16 + lr) * D + 8 * lg]);
            const f16x8 a1 = *reinterpret_cast<const f16x8*>(&k16[(j0 + rf * 16 + lr) * D + 32 + 8 * lg]);
            const float4 r4 = *reinterpret_cast<const float4*>(&rinv[j0 + rf * 16 + lg * 4]);
            #pragma unroll
            for (int rg = 0; rg < RG; ++rg) {
                f32x4 acc = {0.f, 0.f, 0.f, 0.f};
                acc = MFMA16(a0, b[rg][0], acc);
                acc = MFMA16(a1, b[rg][1], acc);
                float4 o;
                o.x = exp2f(acc[0] * r4.x) * Lvi[rg];
                o.y = exp2f(acc[1] * r4.y) * Lvi[rg];
                o.z = exp2f(acc[2] * r4.z) * Lvi[rg];
                o.w = exp2f(acc[3] * r4.w) * Lvi[rg];
                *reinterpret_cast<float4*>(
                    &out[(size_t)(i0 + rg * 16 + lr) * N + j0 + rf * 16 + lg * 4]) = o;
            }
        }
    }
}

extern "C" void kernel_launch(void* const* d_in, const int* in_sizes, int n_in,
                              void* d_out, int out_size, void* d_ws, size_t ws_size,
                              hipStream_t stream)
{
    const float* x   = (const float*)d_in[0];
    const float* Wq1 = (const float*)d_in[1];
    const float* bq1 = (const float*)d_in[2];
    const float* Wq2 = (const float*)d_in[3];
    const float* bq2 = (const float*)d_in[4];
    const float* Wk1 = (const float*)d_in[5];
    const float* bk1 = (const float*)d_in[6];
    const float* Wk2 = (const float*)d_in[7];
    const float* bk2 = (const float*)d_in[8];

    float* out = (float*)d_out;

    _Float16* q16 = (_Float16*)d_ws;                       // 1 MB
    _Float16* k16 = q16 + (size_t)N * D;                   // 1 MB
    float* mpart  = (float*)(k16 + (size_t)N * D);         // SPLIT_S*N
    float* Lpart  = mpart + (size_t)SPLIT_S * N;           // SPLIT_S*N
    float* rinv   = Lpart + (size_t)SPLIT_S * N;           // N
    float* Linv   = rinv + N;                              // N

    k_mlp  <<<N / 4, 256, 0, stream>>>(x, Wq1, bq1, Wq2, bq2, Wk1, bk1, Wk2, bk2, q16, k16);
    k_max  <<<dim3(N / BROWS, SPLIT_S), 256, 0, stream>>>(q16, k16, mpart);
    k_fin1 <<<N / 256, 256, 0, stream>>>(mpart, rinv);
    k_sumL <<<dim3(N / BROWS, SPLIT_S), 256, 0, stream>>>(q16, k16, rinv, Lpart);
    k_finL <<<N / 256, 256, 0, stream>>>(Lpart, Linv);
    k_write<<<dim3(N / BROWS, SPLIT_W), 256, 0, stream>>>(q16, k16, rinv, Linv, out);
}

// Round 12
// 144.405 us; speedup vs baseline: 1.2394x; 1.0240x over previous
//
#include <hip/hip_runtime.h>
#include <math.h>

#define N 8192
#define FIN 129
#define D 64
#define TEMP 10.0f
#define LOG2E 1.4426950408889634f
#define SPLIT_S 32            // j-slices for stats passes (4 blk/CU)
#define SPLIT_W 16            // j-slices for write pass (R7-validated)
#define RG 4                  // row-groups per wave -> 64 rows/wave
#define BROWS 256             // 4 waves * 64 rows

typedef _Float16 f16x8 __attribute__((ext_vector_type(8)));
typedef float    f32x4 __attribute__((ext_vector_type(4)));

#define MFMA16(A, B, C) __builtin_amdgcn_mfma_f32_16x16x32_f16((A), (B), (C), 0, 0, 0)

// Validated geometry (swapped operands, A=k-rows, B=q-rows):
//   B-frag: q row i = i0 + rg*16 + lr   (lr = lane&15)  -> lane's output ROW
//   A-frag: k row j = jr + lr           (jr = 16-row sub-step base)
//   C elem e: col j = jr + lg*4 + e     (lg = lane>>4)
// No-shift softmax: |s2| = |TEMP*log2e*acc/m_j| <~ 30, exp2 never overflows f32.
// All N^2 passes use a software-pipelined register double-buffer: prefetch
// sub-step s+1's k-frags while computing sub-step s (hides ~200-400cy L2 latency).

// ---------------- Kernel 1: q = mlp_q(x), k = mlp_k(x) -> f16 ----------------
__global__ __launch_bounds__(256) void k_mlp(
    const float* __restrict__ x,
    const float* __restrict__ Wq1, const float* __restrict__ bq1,
    const float* __restrict__ Wq2, const float* __restrict__ bq2,
    const float* __restrict__ Wk1, const float* __restrict__ bk1,
    const float* __restrict__ Wk2, const float* __restrict__ bk2,
    _Float16* __restrict__ qo, _Float16* __restrict__ ko)
{
    __shared__ float xs[4][FIN];
    __shared__ float hqs[4][D];
    __shared__ float hks[4][D];
    const int wave = threadIdx.x >> 6;
    const int lane = threadIdx.x & 63;
    const int row  = (blockIdx.x << 2) + wave;

    const float* xr = x + row * FIN;
    xs[wave][lane]      = xr[lane];
    xs[wave][64 + lane] = xr[64 + lane];
    if (lane == 0) xs[wave][128] = xr[128];
    __syncthreads();

    float aq = bq1[lane], ak = bk1[lane];
    for (int f = 0; f < FIN; ++f) {
        const float xv = xs[wave][f];
        aq = fmaf(xv, Wq1[f * D + lane], aq);
        ak = fmaf(xv, Wk1[f * D + lane], ak);
    }
    hqs[wave][lane] = fmaxf(aq, 0.f);
    hks[wave][lane] = fmaxf(ak, 0.f);
    __syncthreads();

    float oq = bq2[lane], ok = bk2[lane];
    for (int t = 0; t < D; ++t) {
        oq = fmaf(hqs[wave][t], Wq2[t * D + lane], oq);
        ok = fmaf(hks[wave][t], Wk2[t * D + lane], ok);
    }
    qo[row * D + lane] = (_Float16)oq;
    ko[row * D + lane] = (_Float16)ok;
}

// ---------------- Pass 1: raw row max -> mpart[SPLIT_S][N] (pipelined) ----------------
__global__ __launch_bounds__(256) void k_max(
    const _Float16* __restrict__ q16, const _Float16* __restrict__ k16,
    float* __restrict__ mpart)
{
    const int tid  = threadIdx.x;
    const int wave = tid >> 6;
    const int lane = tid & 63;
    const int lr   = lane & 15;
    const int lg   = lane >> 4;
    const int i0   = blockIdx.x * BROWS + wave * 64;
    const int jbase = blockIdx.y * (N / SPLIT_S);
    const int S = (N / SPLIT_S) / 16;      // 16 sub-steps of 16 k-rows

    f16x8 b[RG][2];
    #pragma unroll
    for (int rg = 0; rg < RG; ++rg) {
        b[rg][0] = *reinterpret_cast<const f16x8*>(&q16[(i0 + rg * 16 + lr) * D + 8 * lg]);
        b[rg][1] = *reinterpret_cast<const f16x8*>(&q16[(i0 + rg * 16 + lr) * D + 32 + 8 * lg]);
    }

    float mx[RG];
    #pragma unroll
    for (int rg = 0; rg < RG; ++rg) mx[rg] = -INFINITY;

    f16x8 a0[2], a1[2];
    a0[0] = *reinterpret_cast<const f16x8*>(&k16[(jbase + lr) * D + 8 * lg]);
    a1[0] = *reinterpret_cast<const f16x8*>(&k16[(jbase + lr) * D + 32 + 8 * lg]);

    #pragma unroll
    for (int s = 0; s < 16; ++s) {
        const int p = s & 1;
        if (s + 1 < S) {
            const int jr = jbase + (s + 1) * 16;
            a0[1 - p] = *reinterpret_cast<const f16x8*>(&k16[(jr + lr) * D + 8 * lg]);
            a1[1 - p] = *reinterpret_cast<const f16x8*>(&k16[(jr + lr) * D + 32 + 8 * lg]);
        }
        #pragma unroll
        for (int rg = 0; rg < RG; ++rg) {
            f32x4 acc = {0.f, 0.f, 0.f, 0.f};
            acc = MFMA16(a0[p], b[rg][0], acc);
            acc = MFMA16(a1[p], b[rg][1], acc);
            mx[rg] = fmaxf(mx[rg], fmaxf(fmaxf(acc[0], acc[1]), fmaxf(acc[2], acc[3])));
        }
    }

    #pragma unroll
    for (int rg = 0; rg < RG; ++rg) {
        mx[rg] = fmaxf(mx[rg], __shfl_xor(mx[rg], 16));
        mx[rg] = fmaxf(mx[rg], __shfl_xor(mx[rg], 32));
    }
    if (lane < 16) {
        #pragma unroll
        for (int rg = 0; rg < RG; ++rg)
            mpart[blockIdx.y * N + i0 + rg * 16 + lr] = mx[rg];
    }
}

// ---------------- rinv[j] = TEMP*log2e / m_j ----------------
__global__ __launch_bounds__(256) void k_fin1(const float* __restrict__ mp, float* __restrict__ rinv)
{
    const int j = blockIdx.x * 256 + threadIdx.x;
    float m = mp[j];
    #pragma unroll
    for (int s = 1; s < SPLIT_S; ++s) m = fmaxf(m, mp[s * N + j]);
    rinv[j] = TEMP * LOG2E / m;
}

// ---------------- Pass 2: Lpart[s][i] = sum_j exp2(s2_ij) (pipelined) ----------------
__global__ __launch_bounds__(256) void k_sumL(
    const _Float16* __restrict__ q16, const _Float16* __restrict__ k16,
    const float* __restrict__ rinv, float* __restrict__ Lpart)
{
    const int tid  = threadIdx.x;
    const int wave = tid >> 6;
    const int lane = tid & 63;
    const int lr   = lane & 15;
    const int lg   = lane >> 4;
    const int i0   = blockIdx.x * BROWS + wave * 64;
    const int jbase = blockIdx.y * (N / SPLIT_S);
    const int S = (N / SPLIT_S) / 16;

    f16x8 b[RG][2];
    #pragma unroll
    for (int rg = 0; rg < RG; ++rg) {
        b[rg][0] = *reinterpret_cast<const f16x8*>(&q16[(i0 + rg * 16 + lr) * D + 8 * lg]);
        b[rg][1] = *reinterpret_cast<const f16x8*>(&q16[(i0 + rg * 16 + lr) * D + 32 + 8 * lg]);
    }

    float sm[RG];
    #pragma unroll
    for (int rg = 0; rg < RG; ++rg) sm[rg] = 0.f;

    f16x8 a0[2], a1[2];
    float4 r4[2];
    a0[0] = *reinterpret_cast<const f16x8*>(&k16[(jbase + lr) * D + 8 * lg]);
    a1[0] = *reinterpret_cast<const f16x8*>(&k16[(jbase + lr) * D + 32 + 8 * lg]);
    r4[0] = *reinterpret_cast<const float4*>(&rinv[jbase + lg * 4]);

    #pragma unroll
    for (int s = 0; s < 16; ++s) {
        const int p = s & 1;
        if (s + 1 < S) {
            const int jr = jbase + (s + 1) * 16;
            a0[1 - p] = *reinterpret_cast<const f16x8*>(&k16[(jr + lr) * D + 8 * lg]);
            a1[1 - p] = *reinterpret_cast<const f16x8*>(&k16[(jr + lr) * D + 32 + 8 * lg]);
            r4[1 - p] = *reinterpret_cast<const float4*>(&rinv[jr + lg * 4]);
        }
        #pragma unroll
        for (int rg = 0; rg < RG; ++rg) {
            f32x4 acc = {0.f, 0.f, 0.f, 0.f};
            acc = MFMA16(a0[p], b[rg][0], acc);
            acc = MFMA16(a1[p], b[rg][1], acc);
            sm[rg] += exp2f(acc[0] * r4[p].x) + exp2f(acc[1] * r4[p].y)
                    + exp2f(acc[2] * r4[p].z) + exp2f(acc[3] * r4[p].w);
        }
    }

    #pragma unroll
    for (int rg = 0; rg < RG; ++rg) {
        sm[rg] += __shfl_xor(sm[rg], 16);
        sm[rg] += __shfl_xor(sm[rg], 32);
    }
    if (lane < 16) {
        #pragma unroll
        for (int rg = 0; rg < RG; ++rg)
            Lpart[blockIdx.y * N + i0 + rg * 16 + lr] = sm[rg];
    }
}

// ---------------- Linv[i] = 1 / sum_s Lpart[s][i] ----------------
__global__ __launch_bounds__(256) void k_finL(const float* __restrict__ Lp, float* __restrict__ Linv)
{
    const int i = blockIdx.x * 256 + threadIdx.x;
    float L = 0.f;
    #pragma unroll
    for (int s = 0; s < SPLIT_S; ++s) L += Lp[s * N + i];
    Linv[i] = 1.f / L;
}

// ---------------- Pass 3: out = exp2(s2) * Linv_i (pipelined, float4 stores) ----------------
__global__ __launch_bounds__(256) void k_write(
    const _Float16* __restrict__ q16, const _Float16* __restrict__ k16,
    const float* __restrict__ rinv, const float* __restrict__ Linv,
    float* __restrict__ out)
{
    const int tid  = threadIdx.x;
    const int wave = tid >> 6;
    const int lane = tid & 63;
    const int lr   = lane & 15;
    const int lg   = lane >> 4;
    const int i0   = blockIdx.x * BROWS + wave * 64;
    const int jbase = blockIdx.y * (N / SPLIT_W);
    const int S = (N / SPLIT_W) / 16;      // 32 sub-steps

    f16x8 b[RG][2];
    float Lvi[RG];
    #pragma unroll
    for (int rg = 0; rg < RG; ++rg) {
        b[rg][0] = *reinterpret_cast<const f16x8*>(&q16[(i0 + rg * 16 + lr) * D + 8 * lg]);
        b[rg][1] = *reinterpret_cast<const f16x8*>(&q16[(i0 + rg * 16 + lr) * D + 32 + 8 * lg]);
        Lvi[rg] = Linv[i0 + rg * 16 + lr];
    }

    f16x8 a0[2], a1[2];
    float4 r4[2];
    a0[0] = *reinterpret_cast<const f16x8*>(&k16[(jbase + lr) * D + 8 * lg]);
    a1[0] = *reinterpret_cast<const f16x8*>(&k16[(jbase + lr) * D + 32 + 8 * lg]);
    r4[0] = *reinterpret_cast<const float4*>(&rinv[jbase + lg * 4]);

    #pragma unroll
    for (int s = 0; s < 32; ++s) {
        const int p = s & 1;
        const int jr = jbase + s * 16;
        if (s + 1 < S) {
            const int jn = jbase + (s + 1) * 16;
            a0[1 - p] = *reinterpret_cast<const f16x8*>(&k16[(jn + lr) * D + 8 * lg]);
            a1[1 - p] = *reinterpret_cast<const f16x8*>(&k16[(jn + lr) * D + 32 + 8 * lg]);
            r4[1 - p] = *reinterpret_cast<const float4*>(&rinv[jn + lg * 4]);
        }
        #pragma unroll
        for (int rg = 0; rg < RG; ++rg) {
            f32x4 acc = {0.f, 0.f, 0.f, 0.f};
            acc = MFMA16(a0[p], b[rg][0], acc);
            acc = MFMA16(a1[p], b[rg][1], acc);
            float4 o;
            o.x = exp2f(acc[0] * r4[p].x) * Lvi[rg];
            o.y = exp2f(acc[1] * r4[p].y) * Lvi[rg];
            o.z = exp2f(acc[2] * r4[p].z) * Lvi[rg];
            o.w = exp2f(acc[3] * r4[p].w) * Lvi[rg];
            *reinterpret_cast<float4*>(
                &out[(size_t)(i0 + rg * 16 + lr) * N + jr + lg * 4]) = o;
        }
    }
}

extern "C" void kernel_launch(void* const* d_in, const int* in_sizes, int n_in,
                              void* d_out, int out_size, void* d_ws, size_t ws_size,
                              hipStream_t stream)
{
    const float* x   = (const float*)d_in[0];
    const float* Wq1 = (const float*)d_in[1];
    const float* bq1 = (const float*)d_in[2];
    const float* Wq2 = (const float*)d_in[3];
    const float* bq2 = (const float*)d_in[4];
    const float* Wk1 = (const float*)d_in[5];
    const float* bk1 = (const float*)d_in[6];
    const float* Wk2 = (const float*)d_in[7];
    const float* bk2 = (const float*)d_in[8];

    float* out = (float*)d_out;

    _Float16* q16 = (_Float16*)d_ws;                       // 1 MB
    _Float16* k16 = q16 + (size_t)N * D;                   // 1 MB
    float* mpart  = (float*)(k16 + (size_t)N * D);         // SPLIT_S*N
    float* Lpart  = mpart + (size_t)SPLIT_S * N;           // SPLIT_S*N
    float* rinv   = Lpart + (size_t)SPLIT_S * N;           // N
    float* Linv   = rinv + N;                              // N

    k_mlp  <<<N / 4, 256, 0, stream>>>(x, Wq1, bq1, Wq2, bq2, Wk1, bk1, Wk2, bk2, q16, k16);
    k_max  <<<dim3(N / BROWS, SPLIT_S), 256, 0, stream>>>(q16, k16, mpart);
    k_fin1 <<<N / 256, 256, 0, stream>>>(mpart, rinv);
    k_sumL <<<dim3(N / BROWS, SPLIT_S), 256, 0, stream>>>(q16, k16, rinv, Lpart);
    k_finL <<<N / 256, 256, 0, stream>>>(Lpart, Linv);
    k_write<<<dim3(N / BROWS, SPLIT_W), 256, 0, stream>>>(q16, k16, rinv, Linv, out);
}

// Round 13
// 141.148 us; speedup vs baseline: 1.2681x; 1.0231x over previous
//
#include <hip/hip_runtime.h>
#include <math.h>

#define N 8192
#define FIN 129
#define D 64
#define TEMP 10.0f
#define LOG2E 1.4426950408889634f
#define SPLIT_S 32            // j-slices for stats passes (4 blk/CU, R11-validated)
#define SPLIT_W 32            // j-slices for write pass (4 blk/CU, new)
#define RG 4                  // row-groups per wave -> 64 rows/wave
#define BROWS 256             // 4 waves * 64 rows

typedef _Float16 f16x8 __attribute__((ext_vector_type(8)));
typedef float    f32x4 __attribute__((ext_vector_type(4)));

#define MFMA16(A, B, C) __builtin_amdgcn_mfma_f32_16x16x32_f16((A), (B), (C), 0, 0, 0)

// Validated geometry (swapped operands, A=k-rows, B=q-rows):
//   B-frag: q row i = i0 + rg*16 + lr   (lr = lane&15)  -> lane's output ROW
//   A-frag: k row j = jr + lr           (jr = 16-row sub-step base)
//   C elem e: col j = jr + lg*4 + e     (lg = lane>>4)
// No-shift softmax: |s2| = |TEMP*log2e*acc/m_j| <~ 30, exp2 never overflows f32.
// rinv is recomputed per-block from mpart with identical float ops in k_sumL and
// k_write -> bitwise-equal scores -> consistent numerator/denominator.

// ---------------- Kernel 1: q = mlp_q(x), k = mlp_k(x) -> f16 ----------------
__global__ __launch_bounds__(256) void k_mlp(
    const float* __restrict__ x,
    const float* __restrict__ Wq1, const float* __restrict__ bq1,
    const float* __restrict__ Wq2, const float* __restrict__ bq2,
    const float* __restrict__ Wk1, const float* __restrict__ bk1,
    const float* __restrict__ Wk2, const float* __restrict__ bk2,
    _Float16* __restrict__ qo, _Float16* __restrict__ ko)
{
    __shared__ float xs[4][FIN];
    __shared__ float hqs[4][D];
    __shared__ float hks[4][D];
    const int wave = threadIdx.x >> 6;
    const int lane = threadIdx.x & 63;
    const int row  = (blockIdx.x << 2) + wave;

    const float* xr = x + row * FIN;
    xs[wave][lane]      = xr[lane];
    xs[wave][64 + lane] = xr[64 + lane];
    if (lane == 0) xs[wave][128] = xr[128];
    __syncthreads();

    float aq = bq1[lane], ak = bk1[lane];
    for (int f = 0; f < FIN; ++f) {
        const float xv = xs[wave][f];
        aq = fmaf(xv, Wq1[f * D + lane], aq);
        ak = fmaf(xv, Wk1[f * D + lane], ak);
    }
    hqs[wave][lane] = fmaxf(aq, 0.f);
    hks[wave][lane] = fmaxf(ak, 0.f);
    __syncthreads();

    float oq = bq2[lane], ok = bk2[lane];
    for (int t = 0; t < D; ++t) {
        oq = fmaf(hqs[wave][t], Wq2[t * D + lane], oq);
        ok = fmaf(hks[wave][t], Wk2[t * D + lane], ok);
    }
    qo[row * D + lane] = (_Float16)oq;
    ko[row * D + lane] = (_Float16)ok;
}

// ---------------- Pass 1: raw row max -> mpart[SPLIT_S][N] (pipelined) ----------------
__global__ __launch_bounds__(256) void k_max(
    const _Float16* __restrict__ q16, const _Float16* __restrict__ k16,
    float* __restrict__ mpart)
{
    const int tid  = threadIdx.x;
    const int wave = tid >> 6;
    const int lane = tid & 63;
    const int lr   = lane & 15;
    const int lg   = lane >> 4;
    const int i0   = blockIdx.x * BROWS + wave * 64;
    const int jbase = blockIdx.y * (N / SPLIT_S);
    const int S = (N / SPLIT_S) / 16;      // 16 sub-steps of 16 k-rows

    f16x8 b[RG][2];
    #pragma unroll
    for (int rg = 0; rg < RG; ++rg) {
        b[rg][0] = *reinterpret_cast<const f16x8*>(&q16[(i0 + rg * 16 + lr) * D + 8 * lg]);
        b[rg][1] = *reinterpret_cast<const f16x8*>(&q16[(i0 + rg * 16 + lr) * D + 32 + 8 * lg]);
    }

    float mx[RG];
    #pragma unroll
    for (int rg = 0; rg < RG; ++rg) mx[rg] = -INFINITY;

    f16x8 a0[2], a1[2];
    a0[0] = *reinterpret_cast<const f16x8*>(&k16[(jbase + lr) * D + 8 * lg]);
    a1[0] = *reinterpret_cast<const f16x8*>(&k16[(jbase + lr) * D + 32 + 8 * lg]);

    #pragma unroll
    for (int s = 0; s < 16; ++s) {
        const int p = s & 1;
        if (s + 1 < S) {
            const int jr = jbase + (s + 1) * 16;
            a0[1 - p] = *reinterpret_cast<const f16x8*>(&k16[(jr + lr) * D + 8 * lg]);
            a1[1 - p] = *reinterpret_cast<const f16x8*>(&k16[(jr + lr) * D + 32 + 8 * lg]);
        }
        #pragma unroll
        for (int rg = 0; rg < RG; ++rg) {
            f32x4 acc = {0.f, 0.f, 0.f, 0.f};
            acc = MFMA16(a0[p], b[rg][0], acc);
            acc = MFMA16(a1[p], b[rg][1], acc);
            mx[rg] = fmaxf(mx[rg], fmaxf(fmaxf(acc[0], acc[1]), fmaxf(acc[2], acc[3])));
        }
    }

    #pragma unroll
    for (int rg = 0; rg < RG; ++rg) {
        mx[rg] = fmaxf(mx[rg], __shfl_xor(mx[rg], 16));
        mx[rg] = fmaxf(mx[rg], __shfl_xor(mx[rg], 32));
    }
    if (lane < 16) {
        #pragma unroll
        for (int rg = 0; rg < RG; ++rg)
            mpart[blockIdx.y * N + i0 + rg * 16 + lr] = mx[rg];
    }
}

// ---------------- Pass 2: Lpart[s][i] = sum_j exp2(s2_ij); rinv from LDS prologue ----------------
__global__ __launch_bounds__(256) void k_sumL(
    const _Float16* __restrict__ q16, const _Float16* __restrict__ k16,
    const float* __restrict__ mpart, float* __restrict__ Lpart)
{
    const int tid  = threadIdx.x;
    const int wave = tid >> 6;
    const int lane = tid & 63;
    const int lr   = lane & 15;
    const int lg   = lane >> 4;
    const int i0   = blockIdx.x * BROWS + wave * 64;
    const int jbase = blockIdx.y * (N / SPLIT_S);

    __shared__ float rinv_s[N / SPLIT_S];   // 256 cols per slice
    {
        float m = mpart[jbase + tid];
        #pragma unroll
        for (int s = 1; s < SPLIT_S; ++s) m = fmaxf(m, mpart[s * N + jbase + tid]);
        rinv_s[tid] = TEMP * LOG2E / m;
    }

    f16x8 b[RG][2];
    #pragma unroll
    for (int rg = 0; rg < RG; ++rg) {
        b[rg][0] = *reinterpret_cast<const f16x8*>(&q16[(i0 + rg * 16 + lr) * D + 8 * lg]);
        b[rg][1] = *reinterpret_cast<const f16x8*>(&q16[(i0 + rg * 16 + lr) * D + 32 + 8 * lg]);
    }
    __syncthreads();

    float sm[RG];
    #pragma unroll
    for (int rg = 0; rg < RG; ++rg) sm[rg] = 0.f;

    f16x8 a0[2], a1[2];
    a0[0] = *reinterpret_cast<const f16x8*>(&k16[(jbase + lr) * D + 8 * lg]);
    a1[0] = *reinterpret_cast<const f16x8*>(&k16[(jbase + lr) * D + 32 + 8 * lg]);

    #pragma unroll
    for (int s = 0; s < 16; ++s) {
        const int p = s & 1;
        if (s + 1 < 16) {
            const int jr = jbase + (s + 1) * 16;
            a0[1 - p] = *reinterpret_cast<const f16x8*>(&k16[(jr + lr) * D + 8 * lg]);
            a1[1 - p] = *reinterpret_cast<const f16x8*>(&k16[(jr + lr) * D + 32 + 8 * lg]);
        }
        const float4 r4 = *reinterpret_cast<const float4*>(&rinv_s[s * 16 + lg * 4]);
        #pragma unroll
        for (int rg = 0; rg < RG; ++rg) {
            f32x4 acc = {0.f, 0.f, 0.f, 0.f};
            acc = MFMA16(a0[p], b[rg][0], acc);
            acc = MFMA16(a1[p], b[rg][1], acc);
            sm[rg] += exp2f(acc[0] * r4.x) + exp2f(acc[1] * r4.y)
                    + exp2f(acc[2] * r4.z) + exp2f(acc[3] * r4.w);
        }
    }

    #pragma unroll
    for (int rg = 0; rg < RG; ++rg) {
        sm[rg] += __shfl_xor(sm[rg], 16);
        sm[rg] += __shfl_xor(sm[rg], 32);
    }
    if (lane < 16) {
        #pragma unroll
        for (int rg = 0; rg < RG; ++rg)
            Lpart[blockIdx.y * N + i0 + rg * 16 + lr] = sm[rg];
    }
}

// ---------------- Pass 3: out = exp2(s2) * Linv_i; rinv+Linv from LDS prologue ----------------
__global__ __launch_bounds__(256) void k_write(
    const _Float16* __restrict__ q16, const _Float16* __restrict__ k16,
    const float* __restrict__ mpart, const float* __restrict__ Lpart,
    float* __restrict__ out)
{
    const int tid  = threadIdx.x;
    const int wave = tid >> 6;
    const int lane = tid & 63;
    const int lr   = lane & 15;
    const int lg   = lane >> 4;
    const int i0b  = blockIdx.x * BROWS;
    const int i0   = i0b + wave * 64;
    const int jbase = blockIdx.y * (N / SPLIT_W);

    __shared__ float rinv_s[N / SPLIT_W];   // 256 cols per slice
    __shared__ float linv_s[BROWS];         // 256 rows per block
    {
        float m = mpart[jbase + tid];
        #pragma unroll
        for (int s = 1; s < SPLIT_S; ++s) m = fmaxf(m, mpart[s * N + jbase + tid]);
        rinv_s[tid] = TEMP * LOG2E / m;
        float L = Lpart[i0b + tid];
        #pragma unroll
        for (int s = 1; s < SPLIT_S; ++s) L += Lpart[s * N + i0b + tid];
        linv_s[tid] = 1.f / L;
    }

    f16x8 b[RG][2];
    #pragma unroll
    for (int rg = 0; rg < RG; ++rg) {
        b[rg][0] = *reinterpret_cast<const f16x8*>(&q16[(i0 + rg * 16 + lr) * D + 8 * lg]);
        b[rg][1] = *reinterpret_cast<const f16x8*>(&q16[(i0 + rg * 16 + lr) * D + 32 + 8 * lg]);
    }
    __syncthreads();

    float Lvi[RG];
    #pragma unroll
    for (int rg = 0; rg < RG; ++rg) Lvi[rg] = linv_s[wave * 64 + rg * 16 + lr];

    f16x8 a0[2], a1[2];
    a0[0] = *reinterpret_cast<const f16x8*>(&k16[(jbase + lr) * D + 8 * lg]);
    a1[0] = *reinterpret_cast<const f16x8*>(&k16[(jbase + lr) * D + 32 + 8 * lg]);

    #pragma unroll
    for (int s = 0; s < 16; ++s) {
        const int p = s & 1;
        const int jr = jbase + s * 16;
        if (s + 1 < 16) {
            const int jn = jbase + (s + 1) * 16;
            a0[1 - p] = *reinterpret_cast<const f16x8*>(&k16[(jn + lr) * D + 8 * lg]);
            a1[1 - p] = *reinterpret_cast<const f16x8*>(&k16[(jn + lr) * D + 32 + 8 * lg]);
        }
        const float4 r4 = *reinterpret_cast<const float4*>(&rinv_s[s * 16 + lg * 4]);
        #pragma unroll
        for (int rg = 0; rg < RG; ++rg) {
            f32x4 acc = {0.f, 0.f, 0.f, 0.f};
            acc = MFMA16(a0[p], b[rg][0], acc);
            acc = MFMA16(a1[p], b[rg][1], acc);
            float4 o;
            o.x = exp2f(acc[0] * r4.x) * Lvi[rg];
            o.y = exp2f(acc[1] * r4.y) * Lvi[rg];
            o.z = exp2f(acc[2] * r4.z) * Lvi[rg];
            o.w = exp2f(acc[3] * r4.w) * Lvi[rg];
            *reinterpret_cast<float4*>(
                &out[(size_t)(i0 + rg * 16 + lr) * N + jr + lg * 4]) = o;
        }
    }
}

extern "C" void kernel_launch(void* const* d_in, const int* in_sizes, int n_in,
                              void* d_out, int out_size, void* d_ws, size_t ws_size,
                              hipStream_t stream)
{
    const float* x   = (const float*)d_in[0];
    const float* Wq1 = (const float*)d_in[1];
    const float* bq1 = (const float*)d_in[2];
    const float* Wq2 = (const float*)d_in[3];
    const float* bq2 = (const float*)d_in[4];
    const float* Wk1 = (const float*)d_in[5];
    const float* bk1 = (const float*)d_in[6];
    const float* Wk2 = (const float*)d_in[7];
    const float* bk2 = (const float*)d_in[8];

    float* out = (float*)d_out;

    _Float16* q16 = (_Float16*)d_ws;                       // 1 MB
    _Float16* k16 = q16 + (size_t)N * D;                   // 1 MB
    float* mpart  = (float*)(k16 + (size_t)N * D);         // SPLIT_S*N
    float* Lpart  = mpart + (size_t)SPLIT_S * N;           // SPLIT_S*N

    k_mlp  <<<N / 4, 256, 0, stream>>>(x, Wq1, bq1, Wq2, bq2, Wk1, bk1, Wk2, bk2, q16, k16);
    k_max  <<<dim3(N / BROWS, SPLIT_S), 256, 0, stream>>>(q16, k16, mpart);
    k_sumL <<<dim3(N / BROWS, SPLIT_S), 256, 0, stream>>>(q16, k16, mpart, Lpart);
    k_write<<<dim3(N / BROWS, SPLIT_W), 256, 0, stream>>>(q16, k16, mpart, Lpart, out);
}